// Round 9
// baseline (190.794 us; speedup 1.0000x reference)
//
#include <hip/hip_runtime.h>

#define B_   8
#define H_   112
#define W_   112
#define HW_  12544
#define C_   128
#define NH_  4
#define HD_  32
#define KK_  49
#define N_   100352
#define SCALE_ 0.17677669529663687f   // 1/sqrt(32)

typedef __attribute__((ext_vector_type(4))) float floatx4;
typedef __attribute__((ext_vector_type(4))) _Float16 halfx4;
typedef __attribute__((ext_vector_type(8))) _Float16 half8;

// ---------------- K0: weight prep ----------------
// R7: both weight matrices -> single fp16 plane. Error analysis: logits are
// tiny (|q.k|*scale ~ 0.05, softmax near-uniform) so q/k rounding at fp16
// u=2^-11 perturbs the output ~1e-5; v-path adds ~3e-5 after proj.
__global__ __launch_bounds__(256) void k_wt(
    const float* __restrict__ qw, const float* __restrict__ pw,
    _Float16* __restrict__ qwf, _Float16* __restrict__ pwf)
{
  const int idx = blockIdx.x * 256 + threadIdx.x;
  if (idx < 384 * 128) qwf[idx] = (_Float16)qw[idx];
  if (idx < 128 * 128) pwf[idx] = (_Float16)pw[idx];
}

// ---------------- K1: QKV via fp16 MFMA + q.k dot + v store ----------------
// Block = 64 px, 4 waves; wave w = head w. LDS 17.4 KB. R7 form, PINNED at
// 43.8 us (FETCH 25.6 / WRITE 26.7 MB clean).
// Falsified alternatives (do not retry):
//   R1/R2: pass-split + reg caps in split-bf16 regime -> spills.
//   R5: 32-px tile -> MFMA:weight-load ratio halves -> 100 us.
//   R8: 3-pass split + (256,4) in fp16 regime -> total REGRESSED 185.7->189.2
//       (ambiguous attribution; single-pass is the verified optimum).
__global__ __launch_bounds__(256, 2) void k_qkv(
    const float* __restrict__ x, const _Float16* __restrict__ qwf,
    const float* __restrict__ qb,
    _Float16* __restrict__ vbuf, float* __restrict__ dotbuf)
{
  __shared__ __align__(16) _Float16 xf[64 * 136];  // [px][c] fp16
  const int tid = threadIdx.x;
  const int b   = blockIdx.x / 196;
  const int hw0 = (blockIdx.x % 196) * 64;

  { // stage: thread = (c,c+1) x 4 px; coalesced float4 loads, packed writes
    const float* xb = x + (size_t)b * C_ * HW_ + hw0;
    const int p4 = (tid & 15) * 4;
#pragma unroll
    for (int rep = 0; rep < 4; ++rep) {
      const int c = ((tid >> 4) + rep * 16) * 2;
      const float4 fa = *(const float4*)(xb + (size_t)c * HW_ + p4);
      const float4 fb = *(const float4*)(xb + (size_t)(c + 1) * HW_ + p4);
      const float va[4] = {fa.x, fa.y, fa.z, fa.w};
      const float vb[4] = {fb.x, fb.y, fb.z, fb.w};
#pragma unroll
      for (int i = 0; i < 4; ++i) {
        union { _Float16 h[2]; unsigned u; } pk;
        pk.h[0] = (_Float16)va[i];
        pk.h[1] = (_Float16)vb[i];
        *(unsigned*)(xf + (p4 + i) * 136 + c) = pk.u;
      }
    }
  }
  __syncthreads();

  const int w    = __builtin_amdgcn_readfirstlane(tid >> 6);
  const int l    = tid & 63;
  const int m16  = l & 15;
  const int quad = l >> 4;

  int ocbase[6];
#pragma unroll
  for (int g = 0; g < 6; ++g) ocbase[g] = (g >> 1) * 128 + w * 32 + (g & 1) * 16;

  floatx4 acc[6][4];
#pragma unroll
  for (int g = 0; g < 6; ++g)
#pragma unroll
    for (int p = 0; p < 4; ++p) acc[g][p] = (floatx4){0.f, 0.f, 0.f, 0.f};

  for (int ks = 0; ks < 4; ++ks) {
    half8 bb[4];
#pragma unroll
    for (int p = 0; p < 4; ++p) {
      const int off = (p * 16 + m16) * 136 + ks * 32 + quad * 8;
      bb[p] = *(const half8*)(xf + off);
    }
#pragma unroll
    for (int g = 0; g < 6; ++g) {
      const size_t woff = (size_t)(ocbase[g] + m16) * C_ + ks * 32 + quad * 8;
      const half8 wa = *(const half8*)(qwf + woff);
#pragma unroll
      for (int p = 0; p < 4; ++p) {
        acc[g][p] = __builtin_amdgcn_mfma_f32_16x16x32_f16(wa, bb[p], acc[g][p], 0, 0, 0);
      }
    }
  }

  float bias[6][4];
#pragma unroll
  for (int g = 0; g < 6; ++g)
#pragma unroll
    for (int r = 0; r < 4; ++r) bias[g][r] = qb[ocbase[g] + quad * 4 + r];

  const size_t dbase = (size_t)(b * NH_ + w) * HW_ + hw0;

#pragma unroll
  for (int p = 0; p < 4; ++p) {
    float part = 0.f;
#pragma unroll
    for (int t = 0; t < 2; ++t)
#pragma unroll
      for (int r = 0; r < 4; ++r)
        part += (acc[t][p][r] + bias[t][r]) * (acc[2 + t][p][r] + bias[2 + t][r]);
    part += __shfl_xor(part, 16);
    part += __shfl_xor(part, 32);
    if (l < 16) dotbuf[dbase + p * 16 + l] = part * SCALE_;
  }

#pragma unroll
  for (int t = 0; t < 2; ++t) {
#pragma unroll
    for (int p = 0; p < 4; ++p) {
      halfx4 hv;
#pragma unroll
      for (int r = 0; r < 4; ++r) hv[r] = (_Float16)(acc[4 + t][p][r] + bias[4 + t][r]);
      _Float16* vp = vbuf + (dbase + p * 16 + m16) * HD_ + t * 16 + quad * 4;
      *(halfx4*)vp = hv;
    }
  }
}

// ---------------- K2: neighborhood softmax + A*V -> fp16 out --------------
// R9: `at` table fp16 — RETRY of R3 in the NEW regime (rule #23). R3's
// regression was L2 thrash from 6 blk/CU x 62 KB fp32-V windows with NO XCD
// swizzle (FETCH blew to 166 MB). Both confounds are gone now: V fp16
// (31 KB windows) + group-chunked swizzle -> concurrent set ~4 groups x
// 0.8 MB ~ 3.2 MB < 4 MB XCD-L2. fp16 table: LDS 51.2 -> 26.1 KB ->
// 6 blk/CU (Occ 24 -> ~45%), aw = one half8 load. Normalizer sums the
// ROUNDED fp16 e so softmax stays normalized (R3-measured: absmax 2.44e-4).
// TRIPWIRE: k_attn FETCH > 30 MB = thrash returned -> revert table to fp32.
// Kept from R4/R6: fp16 V, XCD-chunked swizzle, fp16 ao output.
__global__ __launch_bounds__(256) void k_attn(
    const _Float16* __restrict__ vbuf, const float* __restrict__ dotbuf,
    const float* __restrict__ rpb, _Float16* __restrict__ aof)
{
  __shared__ __align__(16) _Float16 at[KK_ * 256];   // 25.1 KB
  __shared__ float rsum[256];
  const int tid  = threadIdx.x;
  const int blk  = ((int)blockIdx.x & 7) * 196 + ((int)blockIdx.x >> 3);
  const int head = blk / 392;
  const int rem  = blk % 392;
  const int b    = rem / 49;
  const int t49  = rem % 49;
  const int r0 = (t49 / 7) * 16;
  const int w0 = (t49 % 7) * 16;
  const float* dptr = dotbuf + (size_t)(b * NH_ + head) * HW_;

  {
    const int r = tid >> 4, wv = tid & 15;
    const int gh = r0 + r, gw = w0 + wv;
    float logit[KK_];
    float m = -1e30f;
#pragma unroll
    for (int i = 0; i < 7; ++i) {
      int hr = gh + i; if (hr >= H_) hr -= H_;
      const float* drow = dptr + hr * W_;
#pragma unroll
      for (int j = 0; j < 7; ++j) {
        int wc = gw + j; if (wc >= W_) wc -= W_;
        const float l = drow[wc] + rpb[head * KK_ + i * 7 + j];
        logit[i * 7 + j] = l;
        m = fmaxf(m, l);
      }
    }
    float s = 0.f;
#pragma unroll
    for (int o = 0; o < KK_; ++o) {
      const float e = __expf(logit[o] - m);
      const _Float16 eh = (_Float16)e;
      s += (float)eh;
      at[o * 256 + tid] = eh;
    }
    rsum[tid] = 1.0f / s;
  }
  __syncthreads();

  const int c4  = tid & 7;
  const int seg = tid >> 3;
  const int r   = seg >> 1;
  const int sx  = (seg & 1) * 8;
  const int gh  = r0 + r;
  const int pxb = r * 16 + sx;
  const _Float16* vb = vbuf + (size_t)(b * NH_ + head) * HW_ * HD_ + c4 * 4;

  float4 acc[8];
#pragma unroll
  for (int xx = 0; xx < 8; ++xx) acc[xx] = make_float4(0.f, 0.f, 0.f, 0.f);

  for (int i = 0; i < 7; ++i) {
    int hr = gh + i; if (hr >= H_) hr -= H_;
    float4 win[14];
#pragma unroll
    for (int t = 0; t < 14; ++t) {
      int wc = w0 + sx + t; if (wc >= W_) wc -= W_;
      const halfx4 hv = *(const halfx4*)(vb + ((size_t)hr * W_ + wc) * HD_);
      win[t] = make_float4((float)hv[0], (float)hv[1], (float)hv[2], (float)hv[3]);
    }
#pragma unroll
    for (int j = 0; j < 7; ++j) {
      const half8 a8 = *(const half8*)(at + (i * 7 + j) * 256 + pxb);
      float aw[8];
#pragma unroll
      for (int t = 0; t < 8; ++t) aw[t] = (float)a8[t];
#pragma unroll
      for (int xx = 0; xx < 8; ++xx) {
        acc[xx].x = fmaf(aw[xx], win[xx + j].x, acc[xx].x);
        acc[xx].y = fmaf(aw[xx], win[xx + j].y, acc[xx].y);
        acc[xx].z = fmaf(aw[xx], win[xx + j].z, acc[xx].z);
        acc[xx].w = fmaf(aw[xx], win[xx + j].w, acc[xx].w);
      }
    }
  }

  // out: (B,HW,C) fp16, c = head*32 + c4*4 .. +3 (8B aligned)
  const size_t obase =
      ((size_t)b * HW_ + (size_t)gh * W_ + (w0 + sx)) * C_ + head * HD_ + c4 * 4;
#pragma unroll
  for (int xx = 0; xx < 8; ++xx) {
    const float rs = rsum[pxb + xx];
    halfx4 hv;
    hv[0] = (_Float16)(acc[xx].x * rs);
    hv[1] = (_Float16)(acc[xx].y * rs);
    hv[2] = (_Float16)(acc[xx].z * rs);
    hv[3] = (_Float16)(acc[xx].w * rs);
    *(halfx4*)(aof + obase + (size_t)xx * C_) = hv;
  }
}

// ---------------- K3: proj via fp16 MFMA + NHWC -> NCHW -------------------
// Block = 64 px, 4 waves; wave w -> oc in [w*32, w*32+32). No LDS, no barrier.
// R6: single fp16 ao plane + fp16 weights + mfma_f32_16x16x32_f16 (measured
// win vs bf16 hi/lo split, keep).
__global__ __launch_bounds__(256, 2) void k_proj(
    const _Float16* __restrict__ aof, const _Float16* __restrict__ pwf,
    const float* __restrict__ pb, float* __restrict__ out)
{
  const int tid = threadIdx.x;
  const int b   = blockIdx.x / 196;
  const int hw0 = (blockIdx.x % 196) * 64;
  const int w    = __builtin_amdgcn_readfirstlane(tid >> 6);
  const int l    = tid & 63;
  const int m16  = l & 15;
  const int quad = l >> 4;

  floatx4 acc[2][4];
#pragma unroll
  for (int t = 0; t < 2; ++t)
#pragma unroll
    for (int p = 0; p < 4; ++p) acc[t][p] = (floatx4){0.f, 0.f, 0.f, 0.f};

  const size_t pxbase = (size_t)b * HW_ + hw0;

  for (int ks = 0; ks < 4; ++ks) {
    half8 bb[4];
#pragma unroll
    for (int p = 0; p < 4; ++p) {
      const size_t off = (pxbase + p * 16 + m16) * C_ + ks * 32 + quad * 8;
      bb[p] = *(const half8*)(aof + off);
    }
#pragma unroll
    for (int t = 0; t < 2; ++t) {
      const size_t woff = (size_t)(w * 32 + t * 16 + m16) * C_ + ks * 32 + quad * 8;
      const half8 wa = *(const half8*)(pwf + woff);
#pragma unroll
      for (int p = 0; p < 4; ++p) {
        acc[t][p] = __builtin_amdgcn_mfma_f32_16x16x32_f16(wa, bb[p], acc[t][p], 0, 0, 0);
      }
    }
  }

#pragma unroll
  for (int t = 0; t < 2; ++t) {
    float bias[4];
#pragma unroll
    for (int r = 0; r < 4; ++r) bias[r] = pb[w * 32 + t * 16 + quad * 4 + r];
#pragma unroll
    for (int p = 0; p < 4; ++p) {
#pragma unroll
      for (int r = 0; r < 4; ++r) {
        const int oc = w * 32 + t * 16 + quad * 4 + r;
        out[(size_t)b * C_ * HW_ + (size_t)oc * HW_ + hw0 + p * 16 + m16] =
            acc[t][p][r] + bias[r];
      }
    }
  }
}

extern "C" void kernel_launch(void* const* d_in, const int* in_sizes, int n_in,
                              void* d_out, int out_size, void* d_ws, size_t ws_size,
                              hipStream_t stream) {
  const float* x   = (const float*)d_in[0];
  const float* qw  = (const float*)d_in[1];
  const float* qb  = (const float*)d_in[2];
  const float* rpb = (const float*)d_in[3];
  const float* pw  = (const float*)d_in[4];
  const float* pb  = (const float*)d_in[5];
  float* out = (float*)d_out;

  _Float16* vbuf = (_Float16*)d_ws;                    // N*C fp16 (25.7 MB)
  float* dotb = (float*)(vbuf + (size_t)N_ * C_);      // N*NH fp32 (1.6 MB)
  _Float16* aof = (_Float16*)(dotb + (size_t)N_ * NH_); // N*C fp16 (25.7 MB)
  _Float16* qwf = aof + (size_t)N_ * C_;               // 384*128 fp16
  _Float16* pwf = qwf + 384 * C_;                      // 128*128 fp16

  hipLaunchKernelGGL(k_wt,   dim3(192), dim3(256), 0, stream, qw, pw, qwf, pwf);
  hipLaunchKernelGGL(k_qkv,  dim3(N_ / 64), dim3(256), 0, stream, x, qwf, qb, vbuf, dotb);
  hipLaunchKernelGGL(k_attn, dim3(NH_ * B_ * 49), dim3(256), 0, stream, vbuf, dotb, rpb, aof);
  hipLaunchKernelGGL(k_proj, dim3(N_ / 64), dim3(256), 0, stream, aof, pwf, pb, out);
}

// Round 10
// 183.953 us; speedup vs baseline: 1.0372x; 1.0372x over previous
//
#include <hip/hip_runtime.h>

#define B_   8
#define H_   112
#define W_   112
#define HW_  12544
#define C_   128
#define NH_  4
#define HD_  32
#define KK_  49
#define N_   100352
#define SCALE_ 0.17677669529663687f   // 1/sqrt(32)

typedef __attribute__((ext_vector_type(4))) float floatx4;
typedef __attribute__((ext_vector_type(4))) _Float16 halfx4;
typedef __attribute__((ext_vector_type(8))) _Float16 half8;

// ---------------- K0: weight prep ----------------
// R7: both weight matrices -> single fp16 plane. Error analysis: logits are
// tiny (|q.k|*scale ~ 0.05, softmax near-uniform) so q/k rounding at fp16
// u=2^-11 perturbs the output ~1e-5; v-path adds ~3e-5 after proj.
__global__ __launch_bounds__(256) void k_wt(
    const float* __restrict__ qw, const float* __restrict__ pw,
    _Float16* __restrict__ qwf, _Float16* __restrict__ pwf)
{
  const int idx = blockIdx.x * 256 + threadIdx.x;
  if (idx < 384 * 128) qwf[idx] = (_Float16)qw[idx];
  if (idx < 128 * 128) pwf[idx] = (_Float16)pw[idx];
}

// ---------------- K1: QKV via fp16 MFMA + q.k dot + v store ----------------
// R10: same 64-px tile, re-partitioned over 8 waves (512 threads).
// Wave wid = (w=wid>>1, h=wid&1) owns 3 oc-groups (q,k,v rows
// [w*32+h*16, +16) of each section) -> acc 48 regs/wave (was 96).
// MFMA per weight-frag load stays 4 (R5's failure mode avoided); total
// weight-loads/LDS-reads/traffic per block unchanged — pure re-partition.
// Unavoidable live ~100 regs -> (512,4) cap 128 leaves slack (R1/R2 spilled
// because SINGLE-pass unavoidable live was ~150). q.k combine: both halves
// via 2KB LDS + 1 barrier.
// Falsified (do not retry): R1/R2 pass-split+caps (spill), R5 32-px tile
// (MFMA:load ratio), R8 3-pass fp16 (regressed), R9 fp16 at-table (no gain).
// TRIPWIRE: FETCH/WRITE balloon = spill -> revert to R7 4-wave (256,2) form.
__global__ __launch_bounds__(512, 4) void k_qkv(
    const float* __restrict__ x, const _Float16* __restrict__ qwf,
    const float* __restrict__ qb,
    _Float16* __restrict__ vbuf, float* __restrict__ dotbuf)
{
  __shared__ __align__(16) _Float16 xf[64 * 136];  // [px][c] fp16, 17.4 KB
  __shared__ float dotp[8][64];                    // per-wave q.k partials, 2KB
  const int tid = threadIdx.x;
  const int b   = blockIdx.x / 196;
  const int hw0 = (blockIdx.x % 196) * 64;

  { // stage: 512 threads, thread = (c,c+1) x 4 px; coalesced float4 loads
    const float* xb = x + (size_t)b * C_ * HW_ + hw0;
    const int p4 = (tid & 15) * 4;
#pragma unroll
    for (int rep = 0; rep < 2; ++rep) {
      const int c = ((tid >> 4) + rep * 32) * 2;
      const float4 fa = *(const float4*)(xb + (size_t)c * HW_ + p4);
      const float4 fb = *(const float4*)(xb + (size_t)(c + 1) * HW_ + p4);
      const float va[4] = {fa.x, fa.y, fa.z, fa.w};
      const float vb[4] = {fb.x, fb.y, fb.z, fb.w};
#pragma unroll
      for (int i = 0; i < 4; ++i) {
        union { _Float16 h[2]; unsigned u; } pk;
        pk.h[0] = (_Float16)va[i];
        pk.h[1] = (_Float16)vb[i];
        *(unsigned*)(xf + (p4 + i) * 136 + c) = pk.u;
      }
    }
  }
  __syncthreads();

  const int wid  = __builtin_amdgcn_readfirstlane(tid >> 6);
  const int w    = wid >> 1;        // head
  const int h    = wid & 1;         // hd-half
  const int l    = tid & 63;
  const int m16  = l & 15;
  const int quad = l >> 4;
  const int rowq = w * 32 + h * 16; // q-row base; k = +128, v = +256

  floatx4 acc[3][4];                // [q,k,v][px-group]
#pragma unroll
  for (int g = 0; g < 3; ++g)
#pragma unroll
    for (int p = 0; p < 4; ++p) acc[g][p] = (floatx4){0.f, 0.f, 0.f, 0.f};

  for (int ks = 0; ks < 4; ++ks) {
    half8 bb[4];
#pragma unroll
    for (int p = 0; p < 4; ++p) {
      const int off = (p * 16 + m16) * 136 + ks * 32 + quad * 8;
      bb[p] = *(const half8*)(xf + off);
    }
#pragma unroll
    for (int g = 0; g < 3; ++g) {
      const size_t woff = (size_t)(g * 128 + rowq + m16) * C_ + ks * 32 + quad * 8;
      const half8 wa = *(const half8*)(qwf + woff);
#pragma unroll
      for (int p = 0; p < 4; ++p) {
        acc[g][p] = __builtin_amdgcn_mfma_f32_16x16x32_f16(wa, bb[p], acc[g][p], 0, 0, 0);
      }
    }
  }

  float bq[4], bk[4], bv[4];
#pragma unroll
  for (int r = 0; r < 4; ++r) {
    bq[r] = qb[rowq + quad * 4 + r];
    bk[r] = qb[128 + rowq + quad * 4 + r];
    bv[r] = qb[256 + rowq + quad * 4 + r];
  }

  const size_t dbase = (size_t)(b * NH_ + w) * HW_ + hw0;

  // v store first: get the 26 MB write issued early
#pragma unroll
  for (int p = 0; p < 4; ++p) {
    halfx4 hv;
#pragma unroll
    for (int r = 0; r < 4; ++r) hv[r] = (_Float16)(acc[2][p][r] + bv[r]);
    _Float16* vp = vbuf + (dbase + p * 16 + m16) * HD_ + h * 16 + quad * 4;
    *(halfx4*)vp = hv;
  }

  // q.k partial for this hd-half: sum over r, then quad (shfl), park in LDS
#pragma unroll
  for (int p = 0; p < 4; ++p) {
    float part = 0.f;
#pragma unroll
    for (int r = 0; r < 4; ++r)
      part += (acc[0][p][r] + bq[r]) * (acc[1][p][r] + bk[r]);
    part += __shfl_xor(part, 16);
    part += __shfl_xor(part, 32);
    if (l < 16) dotp[wid][p * 16 + l] = part;
  }
  __syncthreads();

  // combine halves: first 4 waves, wave w2 handles head w2, 64 px each
  if (tid < 256) {
    const int w2 = tid >> 6;
    const int l2 = tid & 63;
    const float s = dotp[w2 * 2][l2] + dotp[w2 * 2 + 1][l2];
    dotbuf[(size_t)(b * NH_ + w2) * HW_ + hw0 + l2] = s * SCALE_;
  }
}

// ---------------- K2: neighborhood softmax + A*V -> fp16 out --------------
// R7 form, VERIFIED BEST — do not touch:
//  - `at` table fp32. fp16 table falsified TWICE: R3 (L2 thrash pre-swizzle)
//    and R9 (no thrash, FETCH clean 13.5 MB, but occupancy did NOT rise —
//    grid 1568 ~ 6 blk/CU already covers capacity — so +400 cvts/thread
//    bought nothing; total 185.7 -> 190.8).
//  - V fp16 (31 KB windows), XCD-chunked swizzle (each (head,b) group's
//    0.8 MB V pinned to one XCD L2), fp16 ao output.
__global__ __launch_bounds__(256) void k_attn(
    const _Float16* __restrict__ vbuf, const float* __restrict__ dotbuf,
    const float* __restrict__ rpb, _Float16* __restrict__ aof)
{
  __shared__ __align__(16) float at[KK_ * 256];
  __shared__ float rsum[256];
  const int tid  = threadIdx.x;
  const int blk  = ((int)blockIdx.x & 7) * 196 + ((int)blockIdx.x >> 3);
  const int head = blk / 392;
  const int rem  = blk % 392;
  const int b    = rem / 49;
  const int t49  = rem % 49;
  const int r0 = (t49 / 7) * 16;
  const int w0 = (t49 % 7) * 16;
  const float* dptr = dotbuf + (size_t)(b * NH_ + head) * HW_;

  {
    const int r = tid >> 4, wv = tid & 15;
    const int gh = r0 + r, gw = w0 + wv;
    float logit[KK_];
    float m = -1e30f;
#pragma unroll
    for (int i = 0; i < 7; ++i) {
      int hr = gh + i; if (hr >= H_) hr -= H_;
      const float* drow = dptr + hr * W_;
#pragma unroll
      for (int j = 0; j < 7; ++j) {
        int wc = gw + j; if (wc >= W_) wc -= W_;
        const float l = drow[wc] + rpb[head * KK_ + i * 7 + j];
        logit[i * 7 + j] = l;
        m = fmaxf(m, l);
      }
    }
    float s = 0.f;
#pragma unroll
    for (int o = 0; o < KK_; ++o) {
      const float e = __expf(logit[o] - m);
      s += e;
      at[o * 256 + tid] = e;
    }
    rsum[tid] = 1.0f / s;
  }
  __syncthreads();

  const int c4  = tid & 7;
  const int seg = tid >> 3;
  const int r   = seg >> 1;
  const int sx  = (seg & 1) * 8;
  const int gh  = r0 + r;
  const int pxb = r * 16 + sx;
  const _Float16* vb = vbuf + (size_t)(b * NH_ + head) * HW_ * HD_ + c4 * 4;

  float4 acc[8];
#pragma unroll
  for (int xx = 0; xx < 8; ++xx) acc[xx] = make_float4(0.f, 0.f, 0.f, 0.f);

  for (int i = 0; i < 7; ++i) {
    int hr = gh + i; if (hr >= H_) hr -= H_;
    float4 win[14];
#pragma unroll
    for (int t = 0; t < 14; ++t) {
      int wc = w0 + sx + t; if (wc >= W_) wc -= W_;
      const halfx4 hv = *(const halfx4*)(vb + ((size_t)hr * W_ + wc) * HD_);
      win[t] = make_float4((float)hv[0], (float)hv[1], (float)hv[2], (float)hv[3]);
    }
#pragma unroll
    for (int j = 0; j < 7; ++j) {
      const float* arow = at + (i * 7 + j) * 256 + pxb;
      const float4 a0 = *(const float4*)arow;
      const float4 a1 = *(const float4*)(arow + 4);
      const float aw[8] = {a0.x, a0.y, a0.z, a0.w, a1.x, a1.y, a1.z, a1.w};
#pragma unroll
      for (int xx = 0; xx < 8; ++xx) {
        acc[xx].x = fmaf(aw[xx], win[xx + j].x, acc[xx].x);
        acc[xx].y = fmaf(aw[xx], win[xx + j].y, acc[xx].y);
        acc[xx].z = fmaf(aw[xx], win[xx + j].z, acc[xx].z);
        acc[xx].w = fmaf(aw[xx], win[xx + j].w, acc[xx].w);
      }
    }
  }

  // out: (B,HW,C) fp16, c = head*32 + c4*4 .. +3 (8B aligned)
  const size_t obase =
      ((size_t)b * HW_ + (size_t)gh * W_ + (w0 + sx)) * C_ + head * HD_ + c4 * 4;
#pragma unroll
  for (int xx = 0; xx < 8; ++xx) {
    const float rs = rsum[pxb + xx];
    halfx4 hv;
    hv[0] = (_Float16)(acc[xx].x * rs);
    hv[1] = (_Float16)(acc[xx].y * rs);
    hv[2] = (_Float16)(acc[xx].z * rs);
    hv[3] = (_Float16)(acc[xx].w * rs);
    *(halfx4*)(aof + obase + (size_t)xx * C_) = hv;
  }
}

// ---------------- K3: proj via fp16 MFMA + NHWC -> NCHW -------------------
// Block = 64 px, 4 waves; wave w -> oc in [w*32, w*32+32). No LDS, no barrier.
// R6: single fp16 ao plane + fp16 weights + mfma_f32_16x16x32_f16 (measured
// win vs bf16 hi/lo split, keep).
__global__ __launch_bounds__(256, 2) void k_proj(
    const _Float16* __restrict__ aof, const _Float16* __restrict__ pwf,
    const float* __restrict__ pb, float* __restrict__ out)
{
  const int tid = threadIdx.x;
  const int b   = blockIdx.x / 196;
  const int hw0 = (blockIdx.x % 196) * 64;
  const int w    = __builtin_amdgcn_readfirstlane(tid >> 6);
  const int l    = tid & 63;
  const int m16  = l & 15;
  const int quad = l >> 4;

  floatx4 acc[2][4];
#pragma unroll
  for (int t = 0; t < 2; ++t)
#pragma unroll
    for (int p = 0; p < 4; ++p) acc[t][p] = (floatx4){0.f, 0.f, 0.f, 0.f};

  const size_t pxbase = (size_t)b * HW_ + hw0;

  for (int ks = 0; ks < 4; ++ks) {
    half8 bb[4];
#pragma unroll
    for (int p = 0; p < 4; ++p) {
      const size_t off = (pxbase + p * 16 + m16) * C_ + ks * 32 + quad * 8;
      bb[p] = *(const half8*)(aof + off);
    }
#pragma unroll
    for (int t = 0; t < 2; ++t) {
      const size_t woff = (size_t)(w * 32 + t * 16 + m16) * C_ + ks * 32 + quad * 8;
      const half8 wa = *(const half8*)(pwf + woff);
#pragma unroll
      for (int p = 0; p < 4; ++p) {
        acc[t][p] = __builtin_amdgcn_mfma_f32_16x16x32_f16(wa, bb[p], acc[t][p], 0, 0, 0);
      }
    }
  }

#pragma unroll
  for (int t = 0; t < 2; ++t) {
    float bias[4];
#pragma unroll
    for (int r = 0; r < 4; ++r) bias[r] = pb[w * 32 + t * 16 + quad * 4 + r];
#pragma unroll
    for (int p = 0; p < 4; ++p) {
#pragma unroll
      for (int r = 0; r < 4; ++r) {
        const int oc = w * 32 + t * 16 + quad * 4 + r;
        out[(size_t)b * C_ * HW_ + (size_t)oc * HW_ + hw0 + p * 16 + m16] =
            acc[t][p][r] + bias[r];
      }
    }
  }
}

extern "C" void kernel_launch(void* const* d_in, const int* in_sizes, int n_in,
                              void* d_out, int out_size, void* d_ws, size_t ws_size,
                              hipStream_t stream) {
  const float* x   = (const float*)d_in[0];
  const float* qw  = (const float*)d_in[1];
  const float* qb  = (const float*)d_in[2];
  const float* rpb = (const float*)d_in[3];
  const float* pw  = (const float*)d_in[4];
  const float* pb  = (const float*)d_in[5];
  float* out = (float*)d_out;

  _Float16* vbuf = (_Float16*)d_ws;                    // N*C fp16 (25.7 MB)
  float* dotb = (float*)(vbuf + (size_t)N_ * C_);      // N*NH fp32 (1.6 MB)
  _Float16* aof = (_Float16*)(dotb + (size_t)N_ * NH_); // N*C fp16 (25.7 MB)
  _Float16* qwf = aof + (size_t)N_ * C_;               // 384*128 fp16
  _Float16* pwf = qwf + 384 * C_;                      // 128*128 fp16

  hipLaunchKernelGGL(k_wt,   dim3(192), dim3(256), 0, stream, qw, pw, qwf, pwf);
  hipLaunchKernelGGL(k_qkv,  dim3(N_ / 64), dim3(512), 0, stream, x, qwf, qb, vbuf, dotb);
  hipLaunchKernelGGL(k_attn, dim3(NH_ * B_ * 49), dim3(256), 0, stream, vbuf, dotb, rpb, aof);
  hipLaunchKernelGGL(k_proj, dim3(N_ / 64), dim3(256), 0, stream, aof, pwf, pb, out);
}